// Round 5
// baseline (332.015 us; speedup 1.0000x reference)
//
#include <hip/hip_runtime.h>
#include <hip/hip_bf16.h>
#include <hip/hip_fp16.h>

// REGATConv on MI355X — round 5.
//   ws: fcb bf16[256*256] | ftb bf16[N*256] | el[N*4] | er[N*4] | offs[N+1] | cursor[N]
//       | rec int4[E]  ({src, half2 ex01, half2 ex23, pad})
//   K1 memset cursor
//   K2 hist_cvt: histogram of dst + fc_w->bf16 convert (fused, independent work)
//   K3 single-block scan -> offs, cursor=start
//   K4 MFMA bf16 GEMM (64x256 tile, wave=head), fused el/er epilogue -> ftb, el, er
//   K5 scatter2: group edges by dst, store packed {src, exp(leaky((el+er)*ew)) fp16 x4}
//   K6 agg3: one wave per dst node, SINGLE pass: o += ex*ft, s += ex; scale by 1/s.

#define NF 256
#define HD 256
#define NH 4

typedef __attribute__((ext_vector_type(8))) short short8;
typedef __attribute__((ext_vector_type(4))) float f32x4;

static __device__ __forceinline__ unsigned short f2bf(float f) {
  unsigned int u = __float_as_uint(f);
  u += 0x7FFFu + ((u >> 16) & 1u);   // RNE
  return (unsigned short)(u >> 16);
}
static __device__ __forceinline__ float bf2f(unsigned short s) {
  return __uint_as_float(((unsigned int)s) << 16);
}
static __device__ __forceinline__ unsigned pkbf(float a, float b) {
  __hip_bfloat162 h = __float22bfloat162_rn(make_float2(a, b));
  return *(unsigned*)&h;
}
static __device__ __forceinline__ int pk2h(float a, float b) {
  __half2 h = __floats2half2_rn(a, b);   // low = a, high = b
  return *(int*)&h;
}
// select head hl's ex out of a packed record
static __device__ __forceinline__ float exsel(int4 r, int hl) {
  int u = (hl < 2) ? r.y : r.z;
  __half2 h = *(__half2*)&u;
  return (hl & 1) ? __high2float(h) : __low2float(h);
}

// fused: dst histogram + fc_w fp32->bf16 convert (first 16384 threads)
__global__ __launch_bounds__(256) void hist_cvt_k(const int* __restrict__ dst,
                                                  int* __restrict__ cursor,
                                                  const float* __restrict__ w,
                                                  unsigned short* __restrict__ o,
                                                  int e) {
  int i = blockIdx.x * 256 + threadIdx.x;
  if (i < 16384) {
    float4 v = ((const float4*)w)[i];
    ((uint2*)o)[i] = make_uint2(pkbf(v.x, v.y), pkbf(v.z, v.w));
  }
  if (i < e) atomicAdd(&cursor[dst[i]], 1);
}

// single-block scan, 1024 thr x 8 elem -> chunk 8192
__global__ __launch_bounds__(1024) void scan_k(int* __restrict__ cursor,
                                               int* __restrict__ offs, int n) {
  __shared__ int wtot[16];
  __shared__ int wexcl[16];
  __shared__ int ctot;
  int tid = threadIdx.x, lane = tid & 63, wid = tid >> 6;
  int carry = 0;
  int nchunk = (n + 8191) >> 13;
  for (int c = 0; c < nchunk; ++c) {
    int base = (c << 13) + tid * 8;
    int v[8];
    if (base + 8 <= n) {
      int4 a = *(const int4*)(cursor + base);
      int4 b = *(const int4*)(cursor + base + 4);
      v[0] = a.x; v[1] = a.y; v[2] = a.z; v[3] = a.w;
      v[4] = b.x; v[5] = b.y; v[6] = b.z; v[7] = b.w;
    } else {
#pragma unroll
      for (int j = 0; j < 8; ++j) v[j] = (base + j < n) ? cursor[base + j] : 0;
    }
    int p[8]; int run = 0;
#pragma unroll
    for (int j = 0; j < 8; ++j) { run += v[j]; p[j] = run; }
    int incl = run;
#pragma unroll
    for (int off = 1; off < 64; off <<= 1) {
      int t = __shfl_up(incl, off);
      if (lane >= off) incl += t;
    }
    if (lane == 63) wtot[wid] = incl;
    __syncthreads();
    if (wid == 0 && lane < 16) {
      int wv = wtot[lane]; int wi = wv;
#pragma unroll
      for (int off = 1; off < 16; off <<= 1) {
        int t = __shfl_up(wi, off);
        if (lane >= off) wi += t;
      }
      wexcl[lane] = wi - wv;
      if (lane == 15) ctot = wi;
    }
    __syncthreads();
    int ebase = carry + wexcl[wid] + (incl - run);
#pragma unroll
    for (int j = 0; j < 8; ++j) {
      int i = base + j;
      if (i < n) { int ex = ebase + p[j] - v[j]; offs[i] = ex; cursor[i] = ex; }
    }
    carry += ctot;
    __syncthreads();
  }
  if (tid == 0) offs[n] = carry;
}

// MFMA GEMM: C[m][o] = sum_k feat[m][k]*fc_w[o][k]. Block: 64 rows x 256 cols,
// 4 waves; wave w owns cols [w*64, w*64+64) == head w. BK=64 (2 mfma k-steps).
__global__ __launch_bounds__(256) void gemm_k(
    const float* __restrict__ feat, const unsigned short* __restrict__ fcb,
    const float* __restrict__ attn_l, const float* __restrict__ attn_r,
    unsigned short* __restrict__ ftb, float* __restrict__ el,
    float* __restrict__ er, int n) {
  __shared__ short aF[4 * 2 * 64 * 8];    // [rt][s][lane][8]  8 KB
  __shared__ short bF[16 * 2 * 64 * 8];   // [cg][s][lane][8] 32 KB
  int tid = threadIdx.x;
  int lane = tid & 63, w = tid >> 6;
  int row0 = blockIdx.x * 64;

  f32x4 acc[4][4];
#pragma unroll
  for (int i = 0; i < 4; ++i)
#pragma unroll
    for (int j = 0; j < 4; ++j) acc[i][j] = (f32x4){0.f, 0.f, 0.f, 0.f};

  int ar = tid >> 2, ak = (tid & 3) << 4;
  int arow = row0 + ar; if (arow >= n) arow = n - 1;
  const float* ap = feat + (size_t)arow * NF + ak;
  int am = ar & 15, art = ar >> 4;
  int s0 = ak >> 5, q0 = (ak >> 3) & 3;
  int s1 = (ak + 8) >> 5, q1 = ((ak + 8) >> 3) & 3;
  short* aw0 = &aF[(((art * 2 + s0) * 64) + q0 * 16 + am) * 8];
  short* aw1 = &aF[(((art * 2 + s1) * 64) + q1 * 16 + am) * 8];

  const unsigned short* bp = fcb + (size_t)tid * NF;
  int bn = tid & 15, bcg = tid >> 4;

  for (int k0 = 0; k0 < NF; k0 += 64) {
    float4 f0 = *(const float4*)(ap + k0);
    float4 f1 = *(const float4*)(ap + k0 + 4);
    float4 f2 = *(const float4*)(ap + k0 + 8);
    float4 f3 = *(const float4*)(ap + k0 + 12);
    uint4 oa = make_uint4(pkbf(f0.x, f0.y), pkbf(f0.z, f0.w),
                          pkbf(f1.x, f1.y), pkbf(f1.z, f1.w));
    uint4 ob = make_uint4(pkbf(f2.x, f2.y), pkbf(f2.z, f2.w),
                          pkbf(f3.x, f3.y), pkbf(f3.z, f3.w));
    *(uint4*)aw0 = oa;
    *(uint4*)aw1 = ob;
#pragma unroll
    for (int o8 = 0; o8 < 8; ++o8) {
      short8 bv = *(const short8*)(bp + k0 + o8 * 8);
      int bs = o8 >> 2, bq = o8 & 3;
      *(short8*)&bF[(((bcg * 2 + bs) * 64) + bq * 16 + bn) * 8] = bv;
    }
    __syncthreads();
#pragma unroll
    for (int s = 0; s < 2; ++s) {
      short8 af[4], bfr[4];
#pragma unroll
      for (int rt = 0; rt < 4; ++rt)
        af[rt] = *(const short8*)&aF[(((rt * 2 + s) * 64) + lane) * 8];
#pragma unroll
      for (int ct = 0; ct < 4; ++ct)
        bfr[ct] = *(const short8*)&bF[((((w * 4 + ct) * 2 + s) * 64) + lane) * 8];
#pragma unroll
      for (int rt = 0; rt < 4; ++rt)
#pragma unroll
        for (int ct = 0; ct < 4; ++ct)
          acc[rt][ct] = __builtin_amdgcn_mfma_f32_16x16x32_bf16(
              af[rt], bfr[ct], acc[rt][ct], 0, 0, 0);
    }
    __syncthreads();
  }

  // epilogue: wave w == head w. C/D map: col = lane&15, row = (lane>>4)*4 + r.
  int ln = lane & 15, lq = lane >> 4;
  float al4[4], ar4[4];
#pragma unroll
  for (int ct = 0; ct < 4; ++ct) {
    al4[ct] = attn_l[w * 64 + ct * 16 + ln];
    ar4[ct] = attn_r[w * 64 + ct * 16 + ln];
  }
#pragma unroll
  for (int rt = 0; rt < 4; ++rt) {
#pragma unroll
    for (int r = 0; r < 4; ++r) {
      float pl = 0.f, pr = 0.f;
#pragma unroll
      for (int ct = 0; ct < 4; ++ct) {
        float v = acc[rt][ct][r];
        pl += v * al4[ct]; pr += v * ar4[ct];
      }
#pragma unroll
      for (int off = 1; off <= 8; off <<= 1) {
        pl += __shfl_xor(pl, off);
        pr += __shfl_xor(pr, off);
      }
      int row = row0 + rt * 16 + lq * 4 + r;
      if (row < n) {
        if (ln == 0) { el[row * NH + w] = pl; er[row * NH + w] = pr; }
        unsigned short* fr = ftb + (size_t)row * HD + w * 64 + ln;
#pragma unroll
        for (int ct = 0; ct < 4; ++ct) fr[ct * 16] = f2bf(acc[rt][ct][r]);
      }
    }
  }
}

// group edges by dst; store one packed 16B record {src, ex01 fp16x2, ex23 fp16x2, 0}
__global__ __launch_bounds__(256) void scatter2_k(
    const int* __restrict__ src, const int* __restrict__ dst,
    const int* __restrict__ efeats, const float* __restrict__ el,
    const float* __restrict__ er, const float* __restrict__ ewt,
    int* __restrict__ cursor, int4* __restrict__ rec, int e) {
  __shared__ float ew_s[32];
  if (threadIdx.x < 32) {
    float v = ewt[threadIdx.x] * 100.0f;
    ew_s[threadIdx.x] = (v >= 0.f) ? v : 0.01f * v;
  }
  __syncthreads();
  int i = blockIdx.x * 256 + threadIdx.x;
  if (i >= e) return;
  int d = dst[i], s = src[i], t = efeats[i] - 1;
  int p = atomicAdd(&cursor[d], 1);
  float4 elv = *(const float4*)(el + (size_t)s * 4);
  float4 erv = *(const float4*)(er + (size_t)d * 4);
  const float* ew = &ew_s[t * 4];
  float x0 = (elv.x + erv.x) * ew[0]; x0 = (x0 >= 0.f) ? x0 : 0.2f * x0;
  float x1 = (elv.y + erv.y) * ew[1]; x1 = (x1 >= 0.f) ? x1 : 0.2f * x1;
  float x2 = (elv.z + erv.z) * ew[2]; x2 = (x2 >= 0.f) ? x2 : 0.2f * x2;
  float x3 = (elv.w + erv.w) * ew[3]; x3 = (x3 >= 0.f) ? x3 : 0.2f * x3;
  int4 r;
  r.x = s;
  r.y = pk2h(__expf(x0), __expf(x1));
  r.z = pk2h(__expf(x2), __expf(x3));
  r.w = 0;
  rec[p] = r;
}

// one wave per dst node; lane owns output cols lane*4..+3 (head hl=lane>>4).
// SINGLE pass: o += ex*ft[src], s += ex; scale by 1/s at the end.
__global__ __launch_bounds__(256) void agg3_k(
    const unsigned short* __restrict__ ftb, const int4* __restrict__ rec,
    const int* __restrict__ offs, float* __restrict__ out, int n) {
  int node = blockIdx.x * 4 + (threadIdx.x >> 6);
  int lane = threadIdx.x & 63;
  if (node >= n) return;
  int start = offs[node];
  int deg = offs[node + 1] - start;
  float o0 = 0.f, o1 = 0.f, o2 = 0.f, o3 = 0.f;
  float s = 0.f;
  int hl = lane >> 4;
  const unsigned short* fb = ftb + (size_t)lane * 4;
  const int4* rp = rec + start;
  if (deg > 0) {
    int i = 0;
    for (; i + 8 <= deg; i += 8) {
      int4 r0 = rp[i],     r1 = rp[i + 1], r2 = rp[i + 2], r3 = rp[i + 3];
      int4 r4 = rp[i + 4], r5 = rp[i + 5], r6 = rp[i + 6], r7 = rp[i + 7];
      ushort4 f0 = *(const ushort4*)(fb + (size_t)r0.x * HD);
      ushort4 f1 = *(const ushort4*)(fb + (size_t)r1.x * HD);
      ushort4 f2 = *(const ushort4*)(fb + (size_t)r2.x * HD);
      ushort4 f3 = *(const ushort4*)(fb + (size_t)r3.x * HD);
      ushort4 f4 = *(const ushort4*)(fb + (size_t)r4.x * HD);
      ushort4 f5 = *(const ushort4*)(fb + (size_t)r5.x * HD);
      ushort4 f6 = *(const ushort4*)(fb + (size_t)r6.x * HD);
      ushort4 f7 = *(const ushort4*)(fb + (size_t)r7.x * HD);
      float e0 = exsel(r0, hl), e1 = exsel(r1, hl), e2 = exsel(r2, hl),
            e3 = exsel(r3, hl), e4 = exsel(r4, hl), e5 = exsel(r5, hl),
            e6 = exsel(r6, hl), e7 = exsel(r7, hl);
      s += ((e0 + e1) + (e2 + e3)) + ((e4 + e5) + (e6 + e7));
      o0 = fmaf(e0, bf2f(f0.x), o0); o1 = fmaf(e0, bf2f(f0.y), o1);
      o2 = fmaf(e0, bf2f(f0.z), o2); o3 = fmaf(e0, bf2f(f0.w), o3);
      o0 = fmaf(e1, bf2f(f1.x), o0); o1 = fmaf(e1, bf2f(f1.y), o1);
      o2 = fmaf(e1, bf2f(f1.z), o2); o3 = fmaf(e1, bf2f(f1.w), o3);
      o0 = fmaf(e2, bf2f(f2.x), o0); o1 = fmaf(e2, bf2f(f2.y), o1);
      o2 = fmaf(e2, bf2f(f2.z), o2); o3 = fmaf(e2, bf2f(f2.w), o3);
      o0 = fmaf(e3, bf2f(f3.x), o0); o1 = fmaf(e3, bf2f(f3.y), o1);
      o2 = fmaf(e3, bf2f(f3.z), o2); o3 = fmaf(e3, bf2f(f3.w), o3);
      o0 = fmaf(e4, bf2f(f4.x), o0); o1 = fmaf(e4, bf2f(f4.y), o1);
      o2 = fmaf(e4, bf2f(f4.z), o2); o3 = fmaf(e4, bf2f(f4.w), o3);
      o0 = fmaf(e5, bf2f(f5.x), o0); o1 = fmaf(e5, bf2f(f5.y), o1);
      o2 = fmaf(e5, bf2f(f5.z), o2); o3 = fmaf(e5, bf2f(f5.w), o3);
      o0 = fmaf(e6, bf2f(f6.x), o0); o1 = fmaf(e6, bf2f(f6.y), o1);
      o2 = fmaf(e6, bf2f(f6.z), o2); o3 = fmaf(e6, bf2f(f6.w), o3);
      o0 = fmaf(e7, bf2f(f7.x), o0); o1 = fmaf(e7, bf2f(f7.y), o1);
      o2 = fmaf(e7, bf2f(f7.z), o2); o3 = fmaf(e7, bf2f(f7.w), o3);
    }
    for (; i < deg; ++i) {
      int4 r0 = rp[i];
      ushort4 f0 = *(const ushort4*)(fb + (size_t)r0.x * HD);
      float e0 = exsel(r0, hl);
      s += e0;
      o0 = fmaf(e0, bf2f(f0.x), o0); o1 = fmaf(e0, bf2f(f0.y), o1);
      o2 = fmaf(e0, bf2f(f0.z), o2); o3 = fmaf(e0, bf2f(f0.w), o3);
    }
    float rs = 1.0f / s;
    o0 *= rs; o1 *= rs; o2 *= rs; o3 *= rs;
  }
  *(float4*)(out + (size_t)node * HD + lane * 4) = make_float4(o0, o1, o2, o3);
}

extern "C" void kernel_launch(void* const* d_in, const int* in_sizes, int n_in,
                              void* d_out, int out_size, void* d_ws, size_t ws_size,
                              hipStream_t stream) {
  const float* feat   = (const float*)d_in[0];
  const int*   src    = (const int*)d_in[1];
  const int*   dst    = (const int*)d_in[2];
  const int*   efeats = (const int*)d_in[3];
  const float* fc_w   = (const float*)d_in[4];
  const float* attn_l = (const float*)d_in[5];
  const float* attn_r = (const float*)d_in[6];
  const float* ewt    = (const float*)d_in[7];
  float* out = (float*)d_out;

  int N = in_sizes[0] / NF;   // 50000
  int E = in_sizes[1];        // 800000

  char* ws = (char*)d_ws;
  size_t off = 0;
  unsigned short* fcb = (unsigned short*)(ws + off); off += (size_t)NF * HD * 2;  // 128 KB
  unsigned short* ftb = (unsigned short*)(ws + off); off += (size_t)N * HD * 2;   // 25.6 MB
  float* el  = (float*)(ws + off);  off += (size_t)N * NH * 4;
  float* er  = (float*)(ws + off);  off += (size_t)N * NH * 4;
  int* offs  = (int*)(ws + off);    off += ((size_t)N + 16) * 4;
  int* cursor = (int*)(ws + off);   off += (size_t)N * 4;
  int4* rec  = (int4*)(ws + off);   off += (size_t)E * 16;                        // 12.8 MB

  hipMemsetAsync(cursor, 0, (size_t)N * 4, stream);
  hist_cvt_k<<<(E + 255) / 256, 256, 0, stream>>>(dst, cursor, fc_w, fcb, E);
  scan_k<<<1, 1024, 0, stream>>>(cursor, offs, N);
  gemm_k<<<(N + 63) / 64, 256, 0, stream>>>(feat, fcb, attn_l, attn_r, ftb, el, er, N);
  scatter2_k<<<(E + 255) / 256, 256, 0, stream>>>(src, dst, efeats, el, er, ewt,
                                                  cursor, rec, E);
  agg3_k<<<(N + 3) / 4, 256, 0, stream>>>(ftb, rec, offs, out, N);
}